// Round 1
// baseline (300.628 us; speedup 1.0000x reference)
//
#include <hip/hip_runtime.h>

// MultiCenterLoss: loss = sum_{label==0} min_c ||f - c + eps||_2 / (count + 1e-5)
// Expansion: ||f-c+eps||^2 = [f2 + 2*eps*fs + eps^2*D] + [c2 - 2*eps*cs] - 2*f.c
// min over c commutes with the per-sample constant.

constexpr int N = 16384;
constexpr int D = 1024;
constexpr int C = 1024;
constexpr float EPS = 1e-6f;

// order-preserving float<->uint map (valid for all finite floats)
__device__ inline unsigned mapf(float f) {
  unsigned b = __float_as_uint(f);
  return (b & 0x80000000u) ? ~b : (b | 0x80000000u);
}
__device__ inline float unmapf(unsigned u) {
  return __uint_as_float((u & 0x80000000u) ? (u ^ 0x80000000u) : ~u);
}

// per-center constant: cc[c] = sum(c^2) - 2*eps*sum(c). One wave per center.
__global__ __launch_bounds__(256) void k_prep(const float* __restrict__ cent,
                                              float* __restrict__ cc) {
  int w = blockIdx.x * 4 + (threadIdx.x >> 6);
  int lane = threadIdx.x & 63;
  const float* row = cent + (size_t)w * D;
  float s1 = 0.f, s2 = 0.f;
#pragma unroll
  for (int j = 0; j < D / 64; ++j) {
    float v = row[lane + 64 * j];
    s1 += v;
    s2 += v * v;
  }
#pragma unroll
  for (int off = 32; off; off >>= 1) {
    s1 += __shfl_down(s1, off);
    s2 += __shfl_down(s2, off);
  }
  if (lane == 0) cc[w] = s2 - 2.0f * EPS * s1;
}

// compact indices with label==0
__global__ __launch_bounds__(256) void k_gather(const int* __restrict__ labels,
                                                unsigned* __restrict__ count,
                                                unsigned* __restrict__ sel) {
  int n = blockIdx.x * 256 + threadIdx.x;
  if (n < N && labels[n] == 0) {
    unsigned slot = atomicAdd(count, 1u);
    sel[slot] = (unsigned)n;
  }
}

// block: 16 selected samples x 256 centers; D chunked by 32; 4x4 micro-tile.
// LDS tiles stored d-major so inner loop reads are float4 / conflict-free.
__global__ __launch_bounds__(256) void k_dist(const float* __restrict__ feat,
                                              const float* __restrict__ cent,
                                              const float* __restrict__ cc,
                                              const unsigned* __restrict__ count,
                                              const unsigned* __restrict__ sel,
                                              unsigned* __restrict__ minmapped) {
  __shared__ float F[32][16];    // [d][sample]
  __shared__ float Cm[32][256];  // [d][center]
  __shared__ unsigned rows[16];

  unsigned cnt = *count;
  unsigned sbase = blockIdx.x * 16;
  if (sbase >= cnt) return;  // static worst-case grid; inactive blocks exit
  unsigned cbase = blockIdx.y * 256;
  int tid = threadIdx.x;
  int tx = tid & 63;   // lane: 64 lanes x 4 centers = 256 centers
  int ty = tid >> 6;   // wave: 4 waves x 4 samples = 16 samples

  if (tid < 16) rows[tid] = sel[min(sbase + (unsigned)tid, cnt - 1u)];
  __syncthreads();

  float acc[4][4] = {};

  for (int d0 = 0; d0 < D; d0 += 32) {
    // stage F tile: 16 rows x 32 d = 128 float4, threads 0..127
    if (tid < 128) {
      int i = tid >> 3;
      int c4 = (tid & 7) * 4;
      const float4 v =
          *(const float4*)(feat + (size_t)rows[i] * D + d0 + c4);
      F[c4 + 0][i] = v.x;
      F[c4 + 1][i] = v.y;
      F[c4 + 2][i] = v.z;
      F[c4 + 3][i] = v.w;
    }
    // stage C tile: 256 rows x 32 d = 2048 float4, 8 per thread
#pragma unroll
    for (int u = 0; u < 8; ++u) {
      int idx = tid + u * 256;
      int r = idx >> 3;
      int c4 = (idx & 7) * 4;
      const float4 v =
          *(const float4*)(cent + (size_t)(cbase + r) * D + d0 + c4);
      Cm[c4 + 0][r] = v.x;
      Cm[c4 + 1][r] = v.y;
      Cm[c4 + 2][r] = v.z;
      Cm[c4 + 3][r] = v.w;
    }
    __syncthreads();

#pragma unroll
    for (int j = 0; j < 32; ++j) {
      float4 fv = *(const float4*)&F[j][ty * 4];
      float4 cv = *(const float4*)&Cm[j][tx * 4];
      float af[4] = {fv.x, fv.y, fv.z, fv.w};
      float cf[4] = {cv.x, cv.y, cv.z, cv.w};
#pragma unroll
      for (int i = 0; i < 4; ++i)
#pragma unroll
        for (int k = 0; k < 4; ++k) acc[i][k] = fmaf(af[i], cf[k], acc[i][k]);
    }
    __syncthreads();
  }

  // epilogue: candidate = cc[c] - 2*fc ; min over this block's 256 centers
  float4 cw = *(const float4*)&cc[cbase + tx * 4];
  float ccv[4] = {cw.x, cw.y, cw.z, cw.w};
  float m[4];
#pragma unroll
  for (int i = 0; i < 4; ++i) {
    float best = 3.4e38f;
#pragma unroll
    for (int k = 0; k < 4; ++k)
      best = fminf(best, ccv[k] - 2.0f * acc[i][k]);
#pragma unroll
    for (int off = 32; off; off >>= 1) best = fminf(best, __shfl_down(best, off));
    m[i] = best;
  }
  if (tx == 0) {
#pragma unroll
    for (int i = 0; i < 4; ++i) {
      unsigned s = sbase + (unsigned)(ty * 4 + i);
      if (s < cnt) atomicMin(&minmapped[s], mapf(m[i]));
    }
  }
}

// per selected sample: ff = sum(f^2) + 2*eps*sum(f) + eps^2*D ; combine + sum
__global__ __launch_bounds__(256) void k_final(const float* __restrict__ feat,
                                               const unsigned* __restrict__ count,
                                               const unsigned* __restrict__ sel,
                                               const unsigned* __restrict__ minmapped,
                                               float* __restrict__ num) {
  unsigned cnt = *count;
  int w = blockIdx.x * 4 + (threadIdx.x >> 6);
  int lane = threadIdx.x & 63;
  for (unsigned slot = (unsigned)w; slot < cnt; slot += 1024u) {
    const float* row = feat + (size_t)sel[slot] * D;
    float s1 = 0.f, s2 = 0.f;
#pragma unroll
    for (int j = 0; j < D / 64; ++j) {
      float v = row[lane + 64 * j];
      s1 += v;
      s2 += v * v;
    }
#pragma unroll
    for (int off = 32; off; off >>= 1) {
      s1 += __shfl_down(s1, off);
      s2 += __shfl_down(s2, off);
    }
    if (lane == 0) {
      float ff = s2 + 2.0f * EPS * s1 + EPS * EPS * (float)D;
      float sq = ff + unmapf(minmapped[slot]);
      atomicAdd(num, sqrtf(fmaxf(sq, 0.0f)));
    }
  }
}

__global__ void k_out(const float* __restrict__ num,
                      const unsigned* __restrict__ count,
                      float* __restrict__ out) {
  out[0] = num[0] / ((float)count[0] + 1e-5f);
}

extern "C" void kernel_launch(void* const* d_in, const int* in_sizes, int n_in,
                              void* d_out, int out_size, void* d_ws, size_t ws_size,
                              hipStream_t stream) {
  const float* feat = (const float*)d_in[0];
  const int* labels = (const int*)d_in[1];
  const float* cent = (const float*)d_in[2];
  float* out = (float*)d_out;

  unsigned* count = (unsigned*)d_ws;                              // 4 B
  float* num = (float*)((char*)d_ws + 4);                         // 4 B
  unsigned* minmapped = (unsigned*)((char*)d_ws + 8);             // N uints
  unsigned* sel = (unsigned*)((char*)d_ws + 8 + 4 * (size_t)N);   // N uints
  float* cc = (float*)((char*)d_ws + 8 + 8 * (size_t)N);          // C floats

  hipMemsetAsync(d_ws, 0, 8, stream);
  hipMemsetAsync(minmapped, 0xFF, sizeof(unsigned) * N, stream);

  k_prep<<<C / 4, 256, 0, stream>>>(cent, cc);
  k_gather<<<N / 256, 256, 0, stream>>>(labels, count, sel);

  dim3 g2(N / 16, 4);  // worst-case sample blocks x 4 center splits
  k_dist<<<g2, 256, 0, stream>>>(feat, cent, cc, count, sel, minmapped);

  k_final<<<256, 256, 0, stream>>>(feat, count, sel, minmapped, num);
  k_out<<<1, 1, 0, stream>>>(num, count, out);
}